// Round 1
// 462.852 us; speedup vs baseline: 1.0138x; 1.0138x over previous
//
#include <hip/hip_runtime.h>
#include <cstdint>
#include <cstddef>

// Problem constants (fixed by reference setup)
#define B_   16
#define M_   512
#define HID_ 768
#define NH_  12
#define HD_  64

typedef short s16x8 __attribute__((ext_vector_type(8)));
typedef float f32x4 __attribute__((ext_vector_type(4)));
typedef unsigned short u16x8 __attribute__((ext_vector_type(8)));
typedef unsigned short u16x4 __attribute__((ext_vector_type(4)));

__device__ __forceinline__ unsigned short f2bf(float f) {
    unsigned int u = __builtin_bit_cast(unsigned int, f);
    u = u + 0x7FFFu + ((u >> 16) & 1u);   // RNE truncate to bf16
    return (unsigned short)(u >> 16);
}

// async global->LDS, 16 B per lane; lds dest = wave-uniform base + lane*16
__device__ __forceinline__ void gld_lds16(const void* g, void* lds) {
    __builtin_amdgcn_global_load_lds(
        (const __attribute__((address_space(1))) unsigned int*)g,
        (__attribute__((address_space(3))) unsigned int*)lds,
        16, 0, 0);
}

// ---------------------------------------------------------------------------
// Pre-pass (fused): blocks [0,3072): X fp32 -> bf16 row-major (8 el/thread).
//                   blocks [3072,3648): W -> bf16 transposed Wt[n][k], 32x32.
// ---------------------------------------------------------------------------
__launch_bounds__(256)
__global__ void prep(const float* __restrict__ X, const float* __restrict__ W,
                     unsigned short* __restrict__ Xb, unsigned short* __restrict__ Wt) {
    __shared__ float T[32][33];
    const int blk = blockIdx.x;
    const int t   = threadIdx.x;
    if (blk < 3072) {
        const size_t i = ((size_t)blk * 256 + t) * 8;
        const float4 a = *(const float4*)(X + i);
        const float4 b = *(const float4*)(X + i + 4);
        u16x8 v = { f2bf(a.x), f2bf(a.y), f2bf(a.z), f2bf(a.w),
                    f2bf(b.x), f2bf(b.y), f2bf(b.z), f2bf(b.w) };
        *(u16x8*)(Xb + i) = v;
    } else {
        const int tb = blk - 3072;            // 0..575
        const int n0 = (tb % 24) * 32;
        const int k0 = (tb / 24) * 32;
        #pragma unroll
        for (int p = 0; p < 4; ++p) {
            const int r = p * 8 + (t >> 5);   // k_local
            const int c = t & 31;             // n_local
            T[r][c] = W[(size_t)(k0 + r) * HID_ + n0 + c];
        }
        __syncthreads();
        const int nl = t >> 3;                // 0..31
        const int k4 = (t & 7) * 4;
        u16x4 v = { f2bf(T[k4 + 0][nl]), f2bf(T[k4 + 1][nl]),
                    f2bf(T[k4 + 2][nl]), f2bf(T[k4 + 3][nl]) };
        *(u16x4*)(Wt + (size_t)(n0 + nl) * HID_ + k0 + k4) = v;
    }
}

// ---------------------------------------------------------------------------
// Kernel 1: Q = X @ Wq + bq via bf16 MFMA 16x16x32. Tile 128x128, BK=64
// (12 k-iters, half the vmcnt-drain barriers of BK=32), 4 waves.
// LDS rows are 128 B -> XOR-swizzle byte ^= ((row&7)<<4) to break the
// 16-way ds_read_b128 bank conflict. global_load_lds writes linearly, so the
// swizzle is applied by pre-swizzling the per-lane GLOBAL source address and
// XOR-ing on the ds_read side (both-sides rule, m104/m201/m231).
//  staging chunk = 8 rows x 128 B = 1024 B: lane -> row lane>>3,
//  stored slot (lane&7)*16  ==> holds logical byte ((lane&7)^(lane>>3))*16.
// ---------------------------------------------------------------------------
__launch_bounds__(256)
__global__ void gemm_qb(const unsigned short* __restrict__ Xb,
                        const unsigned short* __restrict__ Wt,
                        const float* __restrict__ bq, float* __restrict__ Q) {
    __shared__ unsigned short As[128 * 64];   // 16 KB, swizzled layout
    __shared__ unsigned short Bs[128 * 64];

    const int tid  = threadIdx.x;
    const int lane = tid & 63;
    const int wave = tid >> 6;
    const int wr   = (wave >> 1) * 64;
    const int wc   = (wave & 1) * 64;
    const int ln   = lane & 15;
    const int quad = lane >> 4;
    const int r0   = blockIdx.y * 128;
    const int n0   = blockIdx.x * 128;

    // staging geometry (see header comment)
    const int srow  = lane >> 3;                       // 0..7 within chunk
    const int selem = ((lane & 7) ^ (lane >> 3)) * 8;  // bf16 elem (pre-swizzled src)
    const int swz   = (ln & 7) << 4;                   // read-side XOR (row&7 == ln&7)

    f32x4 acc[4][4] = {};

    for (int kt = 0; kt < HID_ / 64; ++kt) {
        const int k0 = kt * 64;
        #pragma unroll
        for (int c = wave * 4; c < wave * 4 + 4; ++c) {
            const unsigned short* ga = Xb + (size_t)(r0 + c * 8 + srow) * HID_ + k0 + selem;
            gld_lds16(ga, (char*)As + c * 1024);
            const unsigned short* gb = Wt + (size_t)(n0 + c * 8 + srow) * HID_ + k0 + selem;
            gld_lds16(gb, (char*)Bs + c * 1024);
        }
        __syncthreads();   // compiler emits s_waitcnt vmcnt(0) before s_barrier

        #pragma unroll
        for (int kk = 0; kk < 2; ++kk) {
            s16x8 af[4], bf[4];
            #pragma unroll
            for (int r = 0; r < 4; ++r)
                af[r] = *(const s16x8*)((const char*)As + (wr + r * 16 + ln) * 128
                                        + ((kk * 64 + quad * 16) ^ swz));
            #pragma unroll
            for (int c = 0; c < 4; ++c)
                bf[c] = *(const s16x8*)((const char*)Bs + (wc + c * 16 + ln) * 128
                                        + ((kk * 64 + quad * 16) ^ swz));
            #pragma unroll
            for (int r = 0; r < 4; ++r)
                #pragma unroll
                for (int c = 0; c < 4; ++c)
                    acc[r][c] = __builtin_amdgcn_mfma_f32_16x16x32_bf16(af[r], bf[c], acc[r][c], 0, 0, 0);
        }
        __syncthreads();
    }

    // epilogue: C/D layout col=lane&15, row=quad*4+reg  [m89-verified]
    #pragma unroll
    for (int c = 0; c < 4; ++c) {
        const int col = n0 + wc + c * 16 + ln;
        const float bias = bq[col];
        #pragma unroll
        for (int r = 0; r < 4; ++r) {
            const int rowb = r0 + wr + r * 16 + quad * 4;
            #pragma unroll
            for (int e = 0; e < 4; ++e)
                Q[(size_t)(rowb + e) * HID_ + col] = acc[r][c][e] + bias;
        }
    }
}

// ---------------------------------------------------------------------------
// Kernel 2a: neighbor dots. One wave per (b, i) row-pair; all 12 heads.
// Lane l reads float4 at chunk c*256 + 4l of rows i and i+1 (1 KiB coalesced
// per wave-instruction), per-lane dot4, then 16-lane shfl_xor segment
// reduce: head = c*4 + (lane>>4). 2048 blocks x 256 thr = 8192 waves.
// ---------------------------------------------------------------------------
__launch_bounds__(256)
__global__ void dots(const float* __restrict__ Q, float* __restrict__ sdot) {
    const int w    = blockIdx.x * 4 + (threadIdx.x >> 6);  // 0..8191
    const int lane = threadIdx.x & 63;
    const int b    = w >> 9;
    const int i    = w & 511;
    if (i >= M_ - 1) return;

    const float* ra = Q + (size_t)(b * M_ + i) * HID_;
    const float* rb = ra + HID_;

    #pragma unroll
    for (int c = 0; c < 3; ++c) {
        const int e = c * 256 + lane * 4;
        const float4 a = *(const float4*)(ra + e);
        const float4 bq4 = *(const float4*)(rb + e);
        float p = a.x * bq4.x + a.y * bq4.y + a.z * bq4.z + a.w * bq4.w;
        #pragma unroll
        for (int off = 1; off < 16; off <<= 1)
            p += __shfl_xor(p, off, 64);
        if ((lane & 15) == 0) {
            const int h = c * 4 + (lane >> 4);
            sdot[(size_t)(b * NH_ + h) * M_ + i] = p * (1.f / 64.f);
        }
    }
}

// ---------------------------------------------------------------------------
// Kernel 2b: per-(b,h) softmax + symmetrize + exclusive log-prefix scan.
// 192 blocks x 512 threads (thread = row i). sdot is L2-resident (393 KB).
// ---------------------------------------------------------------------------
__launch_bounds__(512)
__global__ void scanstats(const float* __restrict__ sdot, const float* __restrict__ prior,
                          const int* __restrict__ mask,
                          float* __restrict__ na_super, float* __restrict__ na_sub,
                          float* __restrict__ Ssum) {
    const int bh = blockIdx.x;
    const int b  = bh / NH_;
    const int i  = threadIdx.x;
    const int lane = i & 63;
    const int wid  = i >> 6;

    __shared__ float sh_s[M_];
    __shared__ float sh_pp[M_];
    __shared__ float wsum[8];

    const float s = (i < M_ - 1) ? sdot[bh * M_ + i] : 0.f;
    sh_s[i] = s;
    __syncthreads();

    const bool vp = (i > 0)      && (mask[b * M_ + i - 1] > 0);
    const bool vn = (i < M_ - 1) && (mask[b * M_ + i + 1] > 0);
    const float sp = vp ? sh_s[i - 1] : -1e30f;
    const float sn = vn ? s : -1e30f;
    const float mx = fmaxf(sp, sn);
    const float ep = vp ? __expf(sp - mx) : 0.f;
    const float en = vn ? __expf(sn - mx) : 0.f;
    float den = ep + en;
    den = (den > 0.f) ? den : 1.f;
    const float pp = ep / den;
    const float pn = en / den;
    sh_pp[i] = pp;
    __syncthreads();

    float Lv = 0.f;
    if (i < M_ - 1) {
        const float  sym = sqrtf(pn * sh_pp[i + 1] + 1e-4f);
        const size_t pb  = (size_t)b * (M_ * M_);
        const float  prs = prior[pb + (size_t)i * M_ + (i + 1)];
        const float  prb = prior[pb + (size_t)(i + 1) * M_ + i];
        const float  nsup = prs + (1.f - prs) * sym;
        na_super[bh * M_ + i] = nsup;
        na_sub[bh * M_ + i]   = prb + (1.f - prb) * sym;
        Lv = logf(nsup + 1e-9f);
    }

    // inclusive wave-shuffle scan, then cross-wave offset, then make exclusive
    float v = Lv;
    #pragma unroll
    for (int off = 1; off < 64; off <<= 1) {
        float tt = __shfl_up(v, off, 64);
        if (lane >= off) v += tt;
    }
    if (lane == 63) wsum[wid] = v;
    __syncthreads();
    float base = 0.f;
    for (int w = 0; w < wid; ++w) base += wsum[w];
    Ssum[bh * M_ + i] = v + base - Lv;   // exclusive prefix
}

// ---------------------------------------------------------------------------
// Kernel 3: dense fill. Block = one (b, row-pair); loops over all 12 heads
// with the prior row held in registers (prior read ONCE from HBM).
// 4096 blocks x 256 threads; 96 KB stored per block, NONTEMPORAL float4
// stores (write-once stream, bypass L2) + nt load of prior (read-once).
// ---------------------------------------------------------------------------
__launch_bounds__(256)
__global__ void fill_out(const float* __restrict__ prior,
                         const float* __restrict__ na_super,
                         const float* __restrict__ na_sub,
                         const float* __restrict__ Ssum,
                         float* __restrict__ out) {
    const int tid = threadIdx.x;
    const int bi  = blockIdx.x;                 // b*256 + ipair
    const int b   = bi >> 8;
    const int i   = ((bi & 255) << 1) | (tid >> 7);
    const int j0  = (tid & 127) * 4;

    const f32x4 pr4 = __builtin_nontemporal_load(
        (const f32x4*)(prior + (size_t)b * (M_ * M_) + (size_t)i * M_ + j0));
    const float pv[4] = {pr4[0], pr4[1], pr4[2], pr4[3]};
    const float c0 = 0.00999999977f;            // sqrtf(1e-4f)
    const size_t half = (size_t)B_ * NH_ * M_ * M_;

    #pragma unroll 2
    for (int h = 0; h < NH_; ++h) {
        const int bh = b * NH_ + h;
        const float4 S4 = *(const float4*)(Ssum + (size_t)bh * M_ + j0);
        const float  Si = Ssum[bh * M_ + i];
        const float  nsup_i   = (i < M_ - 1) ? na_super[bh * M_ + i]   : 0.f;
        const float  nsub_im1 = (i > 0)      ? na_sub[bh * M_ + i - 1] : 0.f;
        const float sv[4] = {S4.x, S4.y, S4.z, S4.w};

        f32x4 nav, ggv;
        #pragma unroll
        for (int e = 0; e < 4; ++e) {
            const int j = j0 + e;
            float na = fmaf(pv[e], 1.f - c0, c0);      // prior + (1-prior)*c0
            if (j == i - 1) na = nsub_im1;
            if (j == i + 1) na = nsup_i;
            const float d = sv[e] - Si;
            float g = __expf((j > i) ? d : -d) + 1e-4f;
            if (j == i) g = na;                        // diag: neibor_attn[i,i]
            nav[e] = na;
            ggv[e] = g;
        }

        const size_t off = ((size_t)(bh * M_ + i)) * M_ + j0;
        __builtin_nontemporal_store(ggv, (f32x4*)(out + off));
        __builtin_nontemporal_store(nav, (f32x4*)(out + half + off));
    }
}

// ---------------------------------------------------------------------------
extern "C" void kernel_launch(void* const* d_in, const int* in_sizes, int n_in,
                              void* d_out, int out_size, void* d_ws, size_t ws_size,
                              hipStream_t stream) {
    const float* X     = (const float*)d_in[0];   // (B, M, HID)
    const float* prior = (const float*)d_in[1];   // (B, 1, M, M)
    const float* Wq    = (const float*)d_in[2];   // (HID, HID)
    const float* bq    = (const float*)d_in[3];   // (HID,)
    const int*   msk   = (const int*)  d_in[4];   // (B, M)
    float* out = (float*)d_out;

    // workspace layout: Q fp32 | na_super | na_sub | Ssum | Xb bf16 | Wt bf16 (~40 MB)
    // sdot (393 KB) aliases Xb: Xb is dead after gemm_qb, sdot written after.
    float* Q        = (float*)d_ws;
    float* na_super = Q + (size_t)B_ * M_ * HID_;
    float* na_sub   = na_super + (size_t)B_ * NH_ * M_;
    float* Ssum     = na_sub   + (size_t)B_ * NH_ * M_;
    unsigned short* Xb = (unsigned short*)(Ssum + (size_t)B_ * NH_ * M_);
    unsigned short* Wt = Xb + (size_t)B_ * M_ * HID_;
    float* sdot     = (float*)Xb;

    prep<<<3072 + 576, 256, 0, stream>>>(X, Wq, Xb, Wt);

    dim3 gg(HID_ / 128, (B_ * M_) / 128);                  // (6, 64)
    gemm_qb<<<gg, 256, 0, stream>>>(Xb, Wt, bq, Q);

    dots<<<2048, 256, 0, stream>>>(Q, sdot);

    scanstats<<<B_ * NH_, M_, 0, stream>>>(sdot, prior, msk, na_super, na_sub, Ssum);

    fill_out<<<B_ * (M_ / 2), 256, 0, stream>>>(prior, na_super, na_sub, Ssum, out);
}

// Round 3
// 457.617 us; speedup vs baseline: 1.0254x; 1.0114x over previous
//
#include <hip/hip_runtime.h>
#include <cstdint>
#include <cstddef>

// Problem constants (fixed by reference setup)
#define B_   16
#define M_   512
#define HID_ 768
#define NH_  12
#define HD_  64

typedef short s16x8 __attribute__((ext_vector_type(8)));
typedef float f32x4 __attribute__((ext_vector_type(4)));
typedef unsigned short u16x8 __attribute__((ext_vector_type(8)));
typedef unsigned short u16x4 __attribute__((ext_vector_type(4)));

__device__ __forceinline__ unsigned short f2bf(float f) {
    unsigned int u = __builtin_bit_cast(unsigned int, f);
    u = u + 0x7FFFu + ((u >> 16) & 1u);   // RNE truncate to bf16
    return (unsigned short)(u >> 16);
}

// async global->LDS, 16 B per lane; lds dest = wave-uniform base + lane*16
__device__ __forceinline__ void gld_lds16(const void* g, void* lds) {
    __builtin_amdgcn_global_load_lds(
        (const __attribute__((address_space(1))) unsigned int*)g,
        (__attribute__((address_space(3))) unsigned int*)lds,
        16, 0, 0);
}

// Cs index: row-major [128][128] fp32 with per-row 5-bit XOR swizzle.
// All Cs accesses are scalar, so 4B-granular XOR is legal. Bank spread:
// dot-phase reads (consecutive rows, same col) -> (d^lane)&31 = 2-way (free).
__device__ __forceinline__ int csx(int r, int c) {
    return (r << 7) | (c ^ (r & 31));
}

// ---------------------------------------------------------------------------
// Pre-pass (fused): blocks [0,3072): X fp32 -> bf16 row-major (8 el/thread).
//                   blocks [3072,3648): W -> bf16 transposed Wt[n][k], 32x32.
// ---------------------------------------------------------------------------
__launch_bounds__(256)
__global__ void prep(const float* __restrict__ X, const float* __restrict__ W,
                     unsigned short* __restrict__ Xb, unsigned short* __restrict__ Wt) {
    __shared__ float T[32][33];
    const int blk = blockIdx.x;
    const int t   = threadIdx.x;
    if (blk < 3072) {
        const size_t i = ((size_t)blk * 256 + t) * 8;
        const float4 a = *(const float4*)(X + i);
        const float4 b = *(const float4*)(X + i + 4);
        u16x8 v = { f2bf(a.x), f2bf(a.y), f2bf(a.z), f2bf(a.w),
                    f2bf(b.x), f2bf(b.y), f2bf(b.z), f2bf(b.w) };
        *(u16x8*)(Xb + i) = v;
    } else {
        const int tb = blk - 3072;            // 0..575
        const int n0 = (tb % 24) * 32;
        const int k0 = (tb / 24) * 32;
        #pragma unroll
        for (int p = 0; p < 4; ++p) {
            const int r = p * 8 + (t >> 5);   // k_local
            const int c = t & 31;             // n_local
            T[r][c] = W[(size_t)(k0 + r) * HID_ + n0 + c];
        }
        __syncthreads();
        const int nl = t >> 3;                // 0..31
        const int k4 = (t & 7) * 4;
        u16x4 v = { f2bf(T[k4 + 0][nl]), f2bf(T[k4 + 1][nl]),
                    f2bf(T[k4 + 2][nl]), f2bf(T[k4 + 3][nl]) };
        *(u16x4*)(Wt + (size_t)(n0 + nl) * HID_ + k0 + k4) = v;
    }
}

// ---------------------------------------------------------------------------
// Kernel 1 (fused): Q = X@Wq + bq via bf16 MFMA, THEN neighbor dots in-block.
// Tile 128x128 (2 heads), BK=64, 4 waves, XOR-swizzled LDS (as round 1).
// Epilogue: C-tile + bias -> Cs (64 KB fp32, XOR-swizzled, aliased over
// As/Bs -- lifetimes disjoint; total LDS 64 KB -> 2 blocks/CU).
// Then: 127 in-tile pair dots per head -> sdot; tile-edge Q rows -> Qedge
// (cross-tile boundary pairs are finished in scanstats).
// fp32 Q never touches HBM (was 25 MB written + ~96 MB re-read).
// Grid: 1D 384 with bijective XCD swizzle so the 6 col-blocks sharing an
// A-panel land on one XCD's L2 (8 rows x 6 cols per XCD: A 1.6MB + B 1.1MB < 4MB).
// ---------------------------------------------------------------------------
__launch_bounds__(256)
__global__ void gemm_dots(const unsigned short* __restrict__ Xb,
                          const unsigned short* __restrict__ Wt,
                          const float* __restrict__ bq,
                          float* __restrict__ sdot, float* __restrict__ Qedge) {
    __shared__ float smem[128 * 128];                      // 64 KB exactly
    unsigned short* As = (unsigned short*)smem;            // 16 KB (K-loop only)
    unsigned short* Bs = (unsigned short*)smem + 128 * 64; // 16 KB (K-loop only)
    float* Cs = smem;                                      // epilogue only

    const int tid  = threadIdx.x;
    const int lane = tid & 63;
    const int wave = tid >> 6;
    const int wr   = (wave >> 1) * 64;
    const int wc   = (wave & 1) * 64;
    const int ln   = lane & 15;
    const int quad = lane >> 4;

    // bijective XCD swizzle: xcd = bid&7 owns rows [xcd*8, xcd*8+8), cols 0..5
    const int bid = blockIdx.x;
    const int li  = bid >> 3;                 // 0..47
    const int by  = ((bid & 7) << 3) + li / 6;
    const int bx  = li % 6;
    const int r0  = by * 128;
    const int n0  = bx * 128;

    // staging geometry: chunk = 8 rows x 128 B; lane -> row lane>>3,
    // stored slot (lane&7)*16 holds logical byte ((lane&7)^(lane>>3))*16.
    const int srow  = lane >> 3;
    const int selem = ((lane & 7) ^ (lane >> 3)) * 8;
    const int swz   = (ln & 7) << 4;          // read-side XOR (row&7 == ln&7)

    f32x4 acc[4][4] = {};

    for (int kt = 0; kt < HID_ / 64; ++kt) {
        const int k0 = kt * 64;
        #pragma unroll
        for (int c = wave * 4; c < wave * 4 + 4; ++c) {
            const unsigned short* ga = Xb + (size_t)(r0 + c * 8 + srow) * HID_ + k0 + selem;
            gld_lds16(ga, (char*)As + c * 1024);
            const unsigned short* gb = Wt + (size_t)(n0 + c * 8 + srow) * HID_ + k0 + selem;
            gld_lds16(gb, (char*)Bs + c * 1024);
        }
        __syncthreads();   // compiler emits s_waitcnt vmcnt(0) before s_barrier

        #pragma unroll
        for (int kk = 0; kk < 2; ++kk) {
            s16x8 af[4], bf[4];
            #pragma unroll
            for (int r = 0; r < 4; ++r)
                af[r] = *(const s16x8*)((const char*)As + (wr + r * 16 + ln) * 128
                                        + ((kk * 64 + quad * 16) ^ swz));
            #pragma unroll
            for (int c = 0; c < 4; ++c)
                bf[c] = *(const s16x8*)((const char*)Bs + (wc + c * 16 + ln) * 128
                                        + ((kk * 64 + quad * 16) ^ swz));
            #pragma unroll
            for (int r = 0; r < 4; ++r)
                #pragma unroll
                for (int c = 0; c < 4; ++c)
                    acc[r][c] = __builtin_amdgcn_mfma_f32_16x16x32_bf16(af[r], bf[c], acc[r][c], 0, 0, 0);
        }
        __syncthreads();   // also protects As/Bs before Cs overwrite (last iter)
    }

    // ---- epilogue A: acc + bias -> Cs  (C/D layout: col=ln, row=quad*4+e)
    #pragma unroll
    for (int c = 0; c < 4; ++c) {
        const int col = wc + c * 16 + ln;
        const float bias = bq[n0 + col];
        #pragma unroll
        for (int r = 0; r < 4; ++r) {
            const int rowb = wr + r * 16 + quad * 4;
            #pragma unroll
            for (int e = 0; e < 4; ++e)
                Cs[csx(rowb + e, col)] = acc[r][c][e] + bias;
        }
    }
    __syncthreads();

    // ---- epilogue B1: export tile-edge Q rows (0 and 127) for boundary pairs
    {
        const int s   = tid >> 7;             // 0: first row, 1: last row
        const int col = tid & 127;
        const int row = s ? 127 : 0;
        Qedge[(size_t)(by * 2 + s) * HID_ + n0 + col] = Cs[csx(row, col)];
    }

    // ---- epilogue B2: in-tile neighbor dots. thread = (pair p, head-half hh)
    // reads: rows p, p+1 at same col -> banks (d^lane)&31 = 2-way, free.
    {
        const int p  = tid & 127;
        const int hh = tid >> 7;
        if (p < 127) {
            const int base = hh * 64;
            float s0 = 0.f, s1 = 0.f;
            #pragma unroll
            for (int d = 0; d < 64; d += 2) {
                s0 += Cs[csx(p,     base + d)]     * Cs[csx(p + 1, base + d)];
                s1 += Cs[csx(p,     base + d + 1)] * Cs[csx(p + 1, base + d + 1)];
            }
            const int g  = by * 128 + p;      // global row
            const int bb = g >> 9;
            const int ii = g & 511;           // in-batch row, always < 511 here
            const int h  = bx * 2 + hh;
            sdot[(size_t)(bb * NH_ + h) * M_ + ii] = (s0 + s1) * (1.f / 64.f);
        }
    }
}

// ---------------------------------------------------------------------------
// Kernel 2: per-(b,h) softmax + symmetrize + exclusive log-prefix scan.
// 192 blocks x 512 threads (thread = row i). sdot is L2/L3-resident (393 KB).
// Cross-tile boundary pairs (i%128==127, i<511) finish their dot from Qedge.
// ---------------------------------------------------------------------------
__launch_bounds__(512)
__global__ void scanstats(const float* __restrict__ sdot, const float* __restrict__ Qedge,
                          const float* __restrict__ prior, const int* __restrict__ mask,
                          float* __restrict__ na_super, float* __restrict__ na_sub,
                          float* __restrict__ Ssum) {
    const int bh = blockIdx.x;
    const int b  = bh / NH_;
    const int h  = bh - b * NH_;
    const int i  = threadIdx.x;
    const int lane = i & 63;
    const int wid  = i >> 6;

    __shared__ float sh_s[M_];
    __shared__ float sh_pp[M_];
    __shared__ float wsum[8];

    float s = 0.f;
    if (i < M_ - 1) {
        if ((i & 127) == 127) {
            // boundary pair: dot(Qedge[last row of tile gby], Qedge[first row of gby+1])
            const int gby = (b << 2) + (i >> 7);
            const float* qa = Qedge + (size_t)(gby * 2 + 1) * HID_ + h * HD_;
            const float* qb = Qedge + (size_t)(gby + 1) * 2 * HID_ + h * HD_;
            float a0 = 0.f, a1 = 0.f;
            #pragma unroll
            for (int d = 0; d < HD_; d += 8) {
                const float4 xa = *(const float4*)(qa + d);
                const float4 xb = *(const float4*)(qb + d);
                const float4 ya = *(const float4*)(qa + d + 4);
                const float4 yb = *(const float4*)(qb + d + 4);
                a0 += xa.x * xb.x + xa.y * xb.y + xa.z * xb.z + xa.w * xb.w;
                a1 += ya.x * yb.x + ya.y * yb.y + ya.z * yb.z + ya.w * yb.w;
            }
            s = (a0 + a1) * (1.f / 64.f);
        } else {
            s = sdot[bh * M_ + i];
        }
    }
    sh_s[i] = s;
    __syncthreads();

    const bool vp = (i > 0)      && (mask[b * M_ + i - 1] > 0);
    const bool vn = (i < M_ - 1) && (mask[b * M_ + i + 1] > 0);
    const float sp = vp ? sh_s[i - 1] : -1e30f;
    const float sn = vn ? s : -1e30f;
    const float mx = fmaxf(sp, sn);
    const float ep = vp ? __expf(sp - mx) : 0.f;
    const float en = vn ? __expf(sn - mx) : 0.f;
    float den = ep + en;
    den = (den > 0.f) ? den : 1.f;
    const float pp = ep / den;
    const float pn = en / den;
    sh_pp[i] = pp;
    __syncthreads();

    float Lv = 0.f;
    if (i < M_ - 1) {
        const float  sym = sqrtf(pn * sh_pp[i + 1] + 1e-4f);
        const size_t pb  = (size_t)b * (M_ * M_);
        const float  prs = prior[pb + (size_t)i * M_ + (i + 1)];
        const float  prb = prior[pb + (size_t)(i + 1) * M_ + i];
        const float  nsup = prs + (1.f - prs) * sym;
        na_super[bh * M_ + i] = nsup;
        na_sub[bh * M_ + i]   = prb + (1.f - prb) * sym;
        Lv = logf(nsup + 1e-9f);
    }

    // inclusive wave-shuffle scan, then cross-wave offset, then make exclusive
    float v = Lv;
    #pragma unroll
    for (int off = 1; off < 64; off <<= 1) {
        float tt = __shfl_up(v, off, 64);
        if (lane >= off) v += tt;
    }
    if (lane == 63) wsum[wid] = v;
    __syncthreads();
    float base = 0.f;
    for (int w = 0; w < wid; ++w) base += wsum[w];
    Ssum[bh * M_ + i] = v + base - Lv;   // exclusive prefix
}

// ---------------------------------------------------------------------------
// Kernel 3: dense fill. Block = one (b, row-pair); loops over all 12 heads
// with the prior row held in registers (prior read ONCE from HBM).
// 4096 blocks x 256 threads; NONTEMPORAL float4 stores (write-once stream).
// ---------------------------------------------------------------------------
__launch_bounds__(256)
__global__ void fill_out(const float* __restrict__ prior,
                         const float* __restrict__ na_super,
                         const float* __restrict__ na_sub,
                         const float* __restrict__ Ssum,
                         float* __restrict__ out) {
    const int tid = threadIdx.x;
    const int bi  = blockIdx.x;                 // b*256 + ipair
    const int b   = bi >> 8;
    const int i   = ((bi & 255) << 1) | (tid >> 7);
    const int j0  = (tid & 127) * 4;

    const f32x4 pr4 = __builtin_nontemporal_load(
        (const f32x4*)(prior + (size_t)b * (M_ * M_) + (size_t)i * M_ + j0));
    const float pv[4] = {pr4[0], pr4[1], pr4[2], pr4[3]};
    const float c0 = 0.00999999977f;            // sqrtf(1e-4f)
    const size_t half = (size_t)B_ * NH_ * M_ * M_;

    #pragma unroll 2
    for (int h = 0; h < NH_; ++h) {
        const int bh = b * NH_ + h;
        const float4 S4 = *(const float4*)(Ssum + (size_t)bh * M_ + j0);
        const float  Si = Ssum[bh * M_ + i];
        const float  nsup_i   = (i < M_ - 1) ? na_super[bh * M_ + i]   : 0.f;
        const float  nsub_im1 = (i > 0)      ? na_sub[bh * M_ + i - 1] : 0.f;
        const float sv[4] = {S4.x, S4.y, S4.z, S4.w};

        f32x4 nav, ggv;
        #pragma unroll
        for (int e = 0; e < 4; ++e) {
            const int j = j0 + e;
            float na = fmaf(pv[e], 1.f - c0, c0);      // prior + (1-prior)*c0
            if (j == i - 1) na = nsub_im1;
            if (j == i + 1) na = nsup_i;
            const float d = sv[e] - Si;
            float g = __expf((j > i) ? d : -d) + 1e-4f;
            if (j == i) g = na;                        // diag: neibor_attn[i,i]
            nav[e] = na;
            ggv[e] = g;
        }

        const size_t off = ((size_t)(bh * M_ + i)) * M_ + j0;
        __builtin_nontemporal_store(ggv, (f32x4*)(out + off));
        __builtin_nontemporal_store(nav, (f32x4*)(out + half + off));
    }
}

// ---------------------------------------------------------------------------
extern "C" void kernel_launch(void* const* d_in, const int* in_sizes, int n_in,
                              void* d_out, int out_size, void* d_ws, size_t ws_size,
                              hipStream_t stream) {
    const float* X     = (const float*)d_in[0];   // (B, M, HID)
    const float* prior = (const float*)d_in[1];   // (B, 1, M, M)
    const float* Wq    = (const float*)d_in[2];   // (HID, HID)
    const float* bq    = (const float*)d_in[3];   // (HID,)
    const int*   msk   = (const int*)  d_in[4];   // (B, M)
    float* out = (float*)d_out;

    // workspace layout (~16 MB): na_super | na_sub | Ssum | sdot | Qedge | Xb | Wt
    float* na_super = (float*)d_ws;
    float* na_sub   = na_super + (size_t)B_ * NH_ * M_;
    float* Ssum     = na_sub   + (size_t)B_ * NH_ * M_;
    float* sdot     = Ssum     + (size_t)B_ * NH_ * M_;
    float* Qedge    = sdot     + (size_t)B_ * NH_ * M_;
    unsigned short* Xb = (unsigned short*)(Qedge + (size_t)64 * 2 * HID_);
    unsigned short* Wt = Xb + (size_t)B_ * M_ * HID_;

    prep<<<3072 + 576, 256, 0, stream>>>(X, Wq, Xb, Wt);

    gemm_dots<<<384, 256, 0, stream>>>(Xb, Wt, bq, sdot, Qedge);

    scanstats<<<B_ * NH_, M_, 0, stream>>>(sdot, Qedge, prior, msk, na_super, na_sub, Ssum);

    fill_out<<<B_ * (M_ / 2), 256, 0, stream>>>(prior, na_super, na_sub, Ssum, out);
}

// Round 4
// 453.663 us; speedup vs baseline: 1.0343x; 1.0087x over previous
//
#include <hip/hip_runtime.h>
#include <cstdint>
#include <cstddef>

// Problem constants (fixed by reference setup)
#define B_   16
#define M_   512
#define HID_ 768
#define NH_  12
#define HD_  64

typedef short s16x8 __attribute__((ext_vector_type(8)));
typedef float f32x4 __attribute__((ext_vector_type(4)));
typedef unsigned short u16x8 __attribute__((ext_vector_type(8)));
typedef unsigned short u16x4 __attribute__((ext_vector_type(4)));

__device__ __forceinline__ unsigned short f2bf(float f) {
    unsigned int u = __builtin_bit_cast(unsigned int, f);
    u = u + 0x7FFFu + ((u >> 16) & 1u);   // RNE truncate to bf16
    return (unsigned short)(u >> 16);
}

// async global->LDS, 16 B per lane; lds dest = wave-uniform base + lane*16
__device__ __forceinline__ void gld_lds16(const void* g, void* lds) {
    __builtin_amdgcn_global_load_lds(
        (const __attribute__((address_space(1))) unsigned int*)g,
        (__attribute__((address_space(3))) unsigned int*)lds,
        16, 0, 0);
}

// Cs index: row-major [64][128] fp32 with per-row 5-bit XOR swizzle.
// All Cs accesses are scalar, so 4B-granular XOR is legal. Bank spread:
// dot-phase reads (consecutive rows, same col) -> (d^lane)&31 = 2-way (free).
__device__ __forceinline__ int csx(int r, int c) {
    return (r << 7) | (c ^ (r & 31));
}

// ---------------------------------------------------------------------------
// Pre-pass (fused): blocks [0,3072): X fp32 -> bf16 row-major (8 el/thread).
//                   blocks [3072,3648): W -> bf16 transposed Wt[n][k], 32x32.
// ---------------------------------------------------------------------------
__launch_bounds__(256)
__global__ void prep(const float* __restrict__ X, const float* __restrict__ W,
                     unsigned short* __restrict__ Xb, unsigned short* __restrict__ Wt) {
    __shared__ float T[32][33];
    const int blk = blockIdx.x;
    const int t   = threadIdx.x;
    if (blk < 3072) {
        const size_t i = ((size_t)blk * 256 + t) * 8;
        const float4 a = *(const float4*)(X + i);
        const float4 b = *(const float4*)(X + i + 4);
        u16x8 v = { f2bf(a.x), f2bf(a.y), f2bf(a.z), f2bf(a.w),
                    f2bf(b.x), f2bf(b.y), f2bf(b.z), f2bf(b.w) };
        *(u16x8*)(Xb + i) = v;
    } else {
        const int tb = blk - 3072;            // 0..575
        const int n0 = (tb % 24) * 32;
        const int k0 = (tb / 24) * 32;
        #pragma unroll
        for (int p = 0; p < 4; ++p) {
            const int r = p * 8 + (t >> 5);   // k_local
            const int c = t & 31;             // n_local
            T[r][c] = W[(size_t)(k0 + r) * HID_ + n0 + c];
        }
        __syncthreads();
        const int nl = t >> 3;                // 0..31
        const int k4 = (t & 7) * 4;
        u16x4 v = { f2bf(T[k4 + 0][nl]), f2bf(T[k4 + 1][nl]),
                    f2bf(T[k4 + 2][nl]), f2bf(T[k4 + 3][nl]) };
        *(u16x4*)(Wt + (size_t)(n0 + nl) * HID_ + k0 + k4) = v;
    }
}

// ---------------------------------------------------------------------------
// Kernel 1 (fused): Q = X@Wq + bq via bf16 MFMA, THEN neighbor dots in-block.
// Tile 64x128 (2 heads), BK=64, 4 waves (2x2, 32x64 each), XOR-swizzled LDS.
// Grid = 128 row-tiles x 6 col-tiles = 768 blocks = EXACTLY 3 blocks/CU
// (round-3's 384 blocks @ 2/CU cap ran at 1.5/CU -> 33% imbalance waste).
// LDS: As 8K + Bs 16K (K-loop) aliased under Cs 64x128 fp32 = 32 KB total.
// Epilogue: bias -> Cs; 63 in-tile pair dots per head (d-split across the
// thread halves, combined via a 512 B LDS partial buf) -> sdot; tile-edge
// rows {0,63} -> Qedge (cross-tile pairs finished in scanstats).
// XCD swizzle: xcd = bid&7 owns row-tiles [xcd*16,+16) x all 6 col-tiles
// (A 1.6 MB + B 1.2 MB < 4 MB L2, bijective).
// ---------------------------------------------------------------------------
__launch_bounds__(256)
__global__ void gemm_dots(const unsigned short* __restrict__ Xb,
                          const unsigned short* __restrict__ Wt,
                          const float* __restrict__ bq,
                          float* __restrict__ sdot, float* __restrict__ Qedge) {
    __shared__ float smem[64 * 128];                       // 32 KB exactly
    __shared__ float partial[128];                         // dot d-split combine
    unsigned short* As = (unsigned short*)smem;            // 8 KB (K-loop only)
    unsigned short* Bs = (unsigned short*)smem + 64 * 64;  // 16 KB (K-loop only)
    float* Cs = smem;                                      // epilogue only

    const int tid  = threadIdx.x;
    const int lane = tid & 63;
    const int wave = tid >> 6;
    const int wr   = (wave >> 1) * 32;
    const int wc   = (wave & 1) * 64;
    const int ln   = lane & 15;
    const int quad = lane >> 4;

    // bijective XCD swizzle: 768 blocks = 8 xcd x (16 row-tiles x 6 col-tiles)
    const int bid = blockIdx.x;
    const int li  = bid >> 3;                 // 0..95
    const int by  = ((bid & 7) << 4) + li / 6;
    const int bx  = li % 6;
    const int r0  = by * 64;
    const int n0  = bx * 128;

    // staging geometry: chunk = 8 rows x 128 B; lane -> row lane>>3,
    // stored slot (lane&7)*16 holds logical byte ((lane&7)^(lane>>3))*16.
    const int srow  = lane >> 3;
    const int selem = ((lane & 7) ^ (lane >> 3)) * 8;
    const int swz   = (ln & 7) << 4;          // read-side XOR (row&7 == ln&7)

    f32x4 acc[2][4] = {};

    for (int kt = 0; kt < HID_ / 64; ++kt) {
        const int k0 = kt * 64;
        // A: 8 chunks (2/wave), B: 16 chunks (4/wave)
        #pragma unroll
        for (int c = wave * 2; c < wave * 2 + 2; ++c) {
            const unsigned short* ga = Xb + (size_t)(r0 + c * 8 + srow) * HID_ + k0 + selem;
            gld_lds16(ga, (char*)As + c * 1024);
        }
        #pragma unroll
        for (int c = wave * 4; c < wave * 4 + 4; ++c) {
            const unsigned short* gb = Wt + (size_t)(n0 + c * 8 + srow) * HID_ + k0 + selem;
            gld_lds16(gb, (char*)Bs + c * 1024);
        }
        __syncthreads();   // compiler emits s_waitcnt vmcnt(0) before s_barrier

        #pragma unroll
        for (int kk = 0; kk < 2; ++kk) {
            s16x8 af[2], bf[4];
            #pragma unroll
            for (int r = 0; r < 2; ++r)
                af[r] = *(const s16x8*)((const char*)As + (wr + r * 16 + ln) * 128
                                        + ((kk * 64 + quad * 16) ^ swz));
            #pragma unroll
            for (int c = 0; c < 4; ++c)
                bf[c] = *(const s16x8*)((const char*)Bs + (wc + c * 16 + ln) * 128
                                        + ((kk * 64 + quad * 16) ^ swz));
            #pragma unroll
            for (int r = 0; r < 2; ++r)
                #pragma unroll
                for (int c = 0; c < 4; ++c)
                    acc[r][c] = __builtin_amdgcn_mfma_f32_16x16x32_bf16(af[r], bf[c], acc[r][c], 0, 0, 0);
        }
        __syncthreads();   // also protects As/Bs before Cs overwrite (last iter)
    }

    // ---- epilogue A: acc + bias -> Cs  (C/D layout: col=ln, row=quad*4+e)
    #pragma unroll
    for (int c = 0; c < 4; ++c) {
        const int col = wc + c * 16 + ln;
        const float bias = bq[n0 + col];
        #pragma unroll
        for (int r = 0; r < 2; ++r) {
            const int rowb = wr + r * 16 + quad * 4;
            #pragma unroll
            for (int e = 0; e < 4; ++e)
                Cs[csx(rowb + e, col)] = acc[r][c][e] + bias;
        }
    }
    __syncthreads();

    // ---- epilogue B1: export tile-edge Q rows (0 and 63) for boundary pairs
    {
        const int s   = tid >> 7;             // 0: first row, 1: last row
        const int col = tid & 127;
        const int row = s ? 63 : 0;
        Qedge[(size_t)(by * 2 + s) * HID_ + n0 + col] = Cs[csx(row, col)];
    }

    // ---- epilogue B2: in-tile neighbor dots, d-split across thread halves.
    // thread = (pair p = tid&63, head-half hh = (tid>>6)&1, d-half dh = tid>>7)
    // reads rows p, p+1 at same col -> banks (d^lane)&31 = 2-way, free.
    {
        const int p  = tid & 63;
        const int hh = (tid >> 6) & 1;
        const int dh = tid >> 7;
        float s0 = 0.f, s1 = 0.f;
        if (p < 63) {
            const int base = hh * 64 + dh * 32;
            #pragma unroll
            for (int d = 0; d < 32; d += 2) {
                s0 += Cs[csx(p, base + d)]     * Cs[csx(p + 1, base + d)];
                s1 += Cs[csx(p, base + d + 1)] * Cs[csx(p + 1, base + d + 1)];
            }
        }
        if (dh) partial[(hh << 6) | p] = s0 + s1;
        __syncthreads();
        if (!dh && p < 63) {
            const float tot = s0 + s1 + partial[(hh << 6) | p];
            const int g  = by * 64 + p;       // global row
            const int bb = g >> 9;
            const int ii = g & 511;           // in-batch row, (ii&63)<63 here
            const int h  = bx * 2 + hh;
            sdot[(size_t)(bb * NH_ + h) * M_ + ii] = tot * (1.f / 64.f);
        }
    }
}

// ---------------------------------------------------------------------------
// Kernel 2: per-(b,h) softmax + symmetrize + exclusive log-prefix scan.
// 192 blocks x 512 threads (thread = row i). sdot is L2/L3-resident (393 KB).
// Cross-tile boundary pairs (i%64==63, i<511) finish their dot from Qedge.
// ---------------------------------------------------------------------------
__launch_bounds__(512)
__global__ void scanstats(const float* __restrict__ sdot, const float* __restrict__ Qedge,
                          const float* __restrict__ prior, const int* __restrict__ mask,
                          float* __restrict__ na_super, float* __restrict__ na_sub,
                          float* __restrict__ Ssum) {
    const int bh = blockIdx.x;
    const int b  = bh / NH_;
    const int h  = bh - b * NH_;
    const int i  = threadIdx.x;
    const int lane = i & 63;
    const int wid  = i >> 6;

    __shared__ float sh_s[M_];
    __shared__ float sh_pp[M_];
    __shared__ float wsum[8];

    float s = 0.f;
    if (i < M_ - 1) {
        if ((i & 63) == 63) {
            // boundary pair: dot(Qedge[last row of tile gby], Qedge[first row of gby+1])
            const int gby = (b << 3) + (i >> 6);
            const float* qa = Qedge + (size_t)(gby * 2 + 1) * HID_ + h * HD_;
            const float* qb = Qedge + (size_t)(gby + 1) * 2 * HID_ + h * HD_;
            float a0 = 0.f, a1 = 0.f;
            #pragma unroll
            for (int d = 0; d < HD_; d += 8) {
                const float4 xa = *(const float4*)(qa + d);
                const float4 xb = *(const float4*)(qb + d);
                const float4 ya = *(const float4*)(qa + d + 4);
                const float4 yb = *(const float4*)(qb + d + 4);
                a0 += xa.x * xb.x + xa.y * xb.y + xa.z * xb.z + xa.w * xb.w;
                a1 += ya.x * yb.x + ya.y * yb.y + ya.z * yb.z + ya.w * yb.w;
            }
            s = (a0 + a1) * (1.f / 64.f);
        } else {
            s = sdot[bh * M_ + i];
        }
    }
    sh_s[i] = s;
    __syncthreads();

    const bool vp = (i > 0)      && (mask[b * M_ + i - 1] > 0);
    const bool vn = (i < M_ - 1) && (mask[b * M_ + i + 1] > 0);
    const float sp = vp ? sh_s[i - 1] : -1e30f;
    const float sn = vn ? s : -1e30f;
    const float mx = fmaxf(sp, sn);
    const float ep = vp ? __expf(sp - mx) : 0.f;
    const float en = vn ? __expf(sn - mx) : 0.f;
    float den = ep + en;
    den = (den > 0.f) ? den : 1.f;
    const float pp = ep / den;
    const float pn = en / den;
    sh_pp[i] = pp;
    __syncthreads();

    float Lv = 0.f;
    if (i < M_ - 1) {
        const float  sym = sqrtf(pn * sh_pp[i + 1] + 1e-4f);
        const size_t pb  = (size_t)b * (M_ * M_);
        const float  prs = prior[pb + (size_t)i * M_ + (i + 1)];
        const float  prb = prior[pb + (size_t)(i + 1) * M_ + i];
        const float  nsup = prs + (1.f - prs) * sym;
        na_super[bh * M_ + i] = nsup;
        na_sub[bh * M_ + i]   = prb + (1.f - prb) * sym;
        Lv = logf(nsup + 1e-9f);
    }

    // inclusive wave-shuffle scan, then cross-wave offset, then make exclusive
    float v = Lv;
    #pragma unroll
    for (int off = 1; off < 64; off <<= 1) {
        float tt = __shfl_up(v, off, 64);
        if (lane >= off) v += tt;
    }
    if (lane == 63) wsum[wid] = v;
    __syncthreads();
    float base = 0.f;
    for (int w = 0; w < wid; ++w) base += wsum[w];
    Ssum[bh * M_ + i] = v + base - Lv;   // exclusive prefix
}

// ---------------------------------------------------------------------------
// Kernel 3: dense fill. Block = one (b, row-pair); loops over all 12 heads
// with the prior row held in registers (prior read ONCE from HBM).
// 4096 blocks x 256 threads; NONTEMPORAL float4 stores (write-once stream).
// ---------------------------------------------------------------------------
__launch_bounds__(256)
__global__ void fill_out(const float* __restrict__ prior,
                         const float* __restrict__ na_super,
                         const float* __restrict__ na_sub,
                         const float* __restrict__ Ssum,
                         float* __restrict__ out) {
    const int tid = threadIdx.x;
    const int bi  = blockIdx.x;                 // b*256 + ipair
    const int b   = bi >> 8;
    const int i   = ((bi & 255) << 1) | (tid >> 7);
    const int j0  = (tid & 127) * 4;

    const f32x4 pr4 = __builtin_nontemporal_load(
        (const f32x4*)(prior + (size_t)b * (M_ * M_) + (size_t)i * M_ + j0));
    const float pv[4] = {pr4[0], pr4[1], pr4[2], pr4[3]};
    const float c0 = 0.00999999977f;            // sqrtf(1e-4f)
    const size_t half = (size_t)B_ * NH_ * M_ * M_;

    #pragma unroll 2
    for (int h = 0; h < NH_; ++h) {
        const int bh = b * NH_ + h;
        const float4 S4 = *(const float4*)(Ssum + (size_t)bh * M_ + j0);
        const float  Si = Ssum[bh * M_ + i];
        const float  nsup_i   = (i < M_ - 1) ? na_super[bh * M_ + i]   : 0.f;
        const float  nsub_im1 = (i > 0)      ? na_sub[bh * M_ + i - 1] : 0.f;
        const float sv[4] = {S4.x, S4.y, S4.z, S4.w};

        f32x4 nav, ggv;
        #pragma unroll
        for (int e = 0; e < 4; ++e) {
            const int j = j0 + e;
            float na = fmaf(pv[e], 1.f - c0, c0);      // prior + (1-prior)*c0
            if (j == i - 1) na = nsub_im1;
            if (j == i + 1) na = nsup_i;
            const float d = sv[e] - Si;
            float g = __expf((j > i) ? d : -d) + 1e-4f;
            if (j == i) g = na;                        // diag: neibor_attn[i,i]
            nav[e] = na;
            ggv[e] = g;
        }

        const size_t off = ((size_t)(bh * M_ + i)) * M_ + j0;
        __builtin_nontemporal_store(ggv, (f32x4*)(out + off));
        __builtin_nontemporal_store(nav, (f32x4*)(out + half + off));
    }
}

// ---------------------------------------------------------------------------
extern "C" void kernel_launch(void* const* d_in, const int* in_sizes, int n_in,
                              void* d_out, int out_size, void* d_ws, size_t ws_size,
                              hipStream_t stream) {
    const float* X     = (const float*)d_in[0];   // (B, M, HID)
    const float* prior = (const float*)d_in[1];   // (B, 1, M, M)
    const float* Wq    = (const float*)d_in[2];   // (HID, HID)
    const float* bq    = (const float*)d_in[3];   // (HID,)
    const int*   msk   = (const int*)  d_in[4];   // (B, M)
    float* out = (float*)d_out;

    // workspace layout (~16 MB): na_super | na_sub | Ssum | sdot | Qedge | Xb | Wt
    float* na_super = (float*)d_ws;
    float* na_sub   = na_super + (size_t)B_ * NH_ * M_;
    float* Ssum     = na_sub   + (size_t)B_ * NH_ * M_;
    float* sdot     = Ssum     + (size_t)B_ * NH_ * M_;
    float* Qedge    = sdot     + (size_t)B_ * NH_ * M_;
    unsigned short* Xb = (unsigned short*)(Qedge + (size_t)128 * 2 * HID_);
    unsigned short* Wt = Xb + (size_t)B_ * M_ * HID_;

    prep<<<3072 + 576, 256, 0, stream>>>(X, Wq, Xb, Wt);

    gemm_dots<<<768, 256, 0, stream>>>(Xb, Wt, bq, sdot, Qedge);

    scanstats<<<B_ * NH_, M_, 0, stream>>>(sdot, Qedge, prior, msk, na_super, na_sub, Ssum);

    fill_out<<<B_ * (M_ / 2), 256, 0, stream>>>(prior, na_super, na_sub, Ssum, out);
}